// Round 15
// baseline (44.274 us; speedup 1.0000x reference)
//
#include <hip/hip_runtime.h>
#include <math.h>

#define CDIM   862
#define NRANK  8
#define KW     7
#define ROWS_PER_BLOCK 4
#define THREADS (ROWS_PER_BLOCK * 64)
#define LN_EPS 1e-5f
#define NTILE  27            // ceil(862/32) element tiles per row
#define XH_LEN 880           // shorts: [0..3] zero pad, [4+i]=bf16(x[i]), zeros to 879
#define XY_LEN 866           // f32: x (later overwritten by pre-norm y), + pad

typedef __attribute__((ext_vector_type(8)))  short bf16x8;
typedef __attribute__((ext_vector_type(16))) float f32x16;

static __device__ __forceinline__ unsigned rne_bf16(float f) {
    const unsigned u = __float_as_uint(f);
    return (u + 0x7FFFu + ((u >> 16) & 1u)) >> 16;   // round-to-nearest-even
}

// One wave = one row. Conv on the matrix pipe:
//   D = A(32x16: Wup bf16, ranks in rows 0-7, taps k=0-6) x B(16x32: windows)
// via mfma_f32_32x32x16_bf16, one MFMA per 32 elements. D layout
// (col=lane&31, row=(reg&3)+8*(reg>>2)+4*(lane>>5), m74/m101-verified):
// lanes 0-31 hold ranks 0-3 of element c=32t+(lane&31) in d[0..3], lanes
// 32-63 ranks 4-7 -> GELU lane-balanced; down-proj closes with shfl_xor(32).
// ROUND-15 FIX: window extraction is 16-bit-granular (shift in {0,16}) --
// v_alignbit_b32's shift is S2[4:0] (5 bits), so round 14's byte-granular
// shift (32/48 for c%4 in {1,2}) silently wrapped and corrupted half the
// windows. Also: x staged to bf16 with RNE instead of truncation.
__global__ __launch_bounds__(THREADS) void cvmc_kernel(
    const float* __restrict__ x,
    const float* __restrict__ Wup,
    const float* __restrict__ bup,
    const float* __restrict__ Wdown,
    const float* __restrict__ bdown,
    const float* __restrict__ gamma,
    const float* __restrict__ beta,
    float* __restrict__ out)
{
    const int lane = threadIdx.x & 63;
    const int wv   = threadIdx.x >> 6;
    const int row  = blockIdx.x * ROWS_PER_BLOCK + wv;

    __shared__ short sxh[ROWS_PER_BLOCK][XH_LEN];
    __shared__ float sxy[ROWS_PER_BLOCK][XY_LEN];

    // ---- per-lane rank weights: this half-wave owns ranks rbase..rbase+3 ----
    const int hh    = lane >> 5;
    const int rbase = 4 * hh;
    float bu4[4], wd4[4];
#pragma unroll
    for (int q = 0; q < 4; ++q) {
        bu4[q] = bup[rbase + q];
        wd4[q] = Wdown[rbase + q];
    }
    const float bdv = bdown[0];

    // ---- A fragment: row = lane&31 (rank), k-slot j (lanes 0-31 cover k=0-7) ----
    bf16x8 afrag;
    {
        const int r = lane & 31;
        const bool arow = (hh == 0) && (r < NRANK);
#pragma unroll
        for (int j = 0; j < 8; ++j) {
            float wvv = 0.0f;
            if (arow && j < KW) wvv = Wup[r * KW + j];
            afrag[j] = (short)(rne_bf16(wvv) & 0xFFFFu);
        }
    }

    // ---- stage row: sxy = f32 x, sxh = bf16(RNE) with 4-short left pad ----
    {
        const float2* __restrict__ xr2 =
            reinterpret_cast<const float2*>(x + (size_t)row * CDIM);
        unsigned* xhW = reinterpret_cast<unsigned*>(&sxh[wv][0]);
#pragma unroll
        for (int qq = 0; qq < 7; ++qq) {
            const int i = lane + 64 * qq;               // float2 pair index
            if (i < CDIM / 2) {
                float2 v = xr2[i];
                *reinterpret_cast<float2*>(&sxy[wv][2 * i]) = v;
                xhW[2 + i] = rne_bf16(v.x) | (rne_bf16(v.y) << 16);  // shorts 4+2i,5+2i
            }
        }
        if (lane < 2)       xhW[lane] = 0u;             // shorts 0..3 (left halo)
        else if (lane < 9)  xhW[431 + lane] = 0u;       // dwords 433..439 = shorts 866..879
        else if (lane < 13) sxy[wv][862 + (lane - 9)] = 0.0f;   // xy pad
    }
    // Same-wave DS ops are processed in issue order; wave-private slice -> no barrier.

    const float C1 = -0.0713548162f;   // gelu(t) ~ t*sigmoid(1.5957691 t + 0.07135482 t^3)
    const float C0 = -1.5957691216f;

    f32x16 zero16;
#pragma unroll
    for (int i = 0; i < 16; ++i) zero16[i] = 0.0f;

    float sum = 0.0f, sumsq = 0.0f;

    const unsigned* xhD = reinterpret_cast<const unsigned*>(&sxh[wv][0]);
    const int l31 = lane & 31;

    for (int t = 0; t < NTILE; ++t) {
        const int c  = 32 * t + l31;       // this lane's output element
        const int ws = c + 1;              // short index of window start x[c-3] (sxh[4+c-3])

        // ---- B fragment: 8 bf16 window x[c-3..c+4]; 16-bit-granular extraction ----
        const unsigned* pw = xhD + (ws >> 1);
        const unsigned sh = (unsigned)(ws & 1) * 16u;   // 0 or 16: within S2[4:0]
        const unsigned q0 = pw[0], q1 = pw[1], q2 = pw[2], q3 = pw[3], q4 = pw[4];
        union { unsigned u[4]; bf16x8 v; } bfr;
        bfr.u[0] = __builtin_amdgcn_alignbit(q1, q0, sh);
        bfr.u[1] = __builtin_amdgcn_alignbit(q2, q1, sh);
        bfr.u[2] = __builtin_amdgcn_alignbit(q3, q2, sh);
        bfr.u[3] = __builtin_amdgcn_alignbit(q4, q3, sh);

        // conv on the matrix pipe: d[q] = conv of rank (rbase+q) at element c
        f32x16 d = __builtin_amdgcn_mfma_f32_32x32x16_bf16(afrag, bfr.v, zero16, 0, 0, 0);

        float t0 = d[0] + bu4[0];
        float t1 = d[1] + bu4[1];
        float t2 = d[2] + bu4[2];
        float t3 = d[3] + bu4[3];

        // GELU + down-proj partial (rank-paired rcp), same math as r6-r13
        const float z0 = t0 * fmaf(t0 * t0, C1, C0);
        const float z1 = t1 * fmaf(t1 * t1, C1, C0);
        const float z2 = t2 * fmaf(t2 * t2, C1, C0);
        const float z3 = t3 * fmaf(t3 * t3, C1, C0);
        const float u0 = 1.0f + __expf(z0);
        const float u1 = 1.0f + __expf(z1);
        const float u2 = 1.0f + __expf(z2);
        const float u3 = 1.0f + __expf(z3);
        const float r01 = __builtin_amdgcn_rcpf(u0 * u1);
        const float r23 = __builtin_amdgcn_rcpf(u2 * u3);
        float n0 = (wd4[0] * t0) * u1; n0 = fmaf(wd4[1] * t1, u0, n0);
        float n1 = (wd4[2] * t2) * u3; n1 = fmaf(wd4[3] * t3, u2, n1);
        float p  = n0 * r01;
        p = fmaf(n1, r23, p);

        const float psum = p + __shfl_xor(p, 32, 64);   // both halves -> full h

        const float xv = sxy[wv][c];
        float y = xv + bdv + psum;                      // residual (+down bias once)
        if (c >= CDIM) y = 0.0f;                        // tile-26 tail mask
        if (lane < 32) sxy[wv][c] = y;                  // pre-norm y buffer
        sum += y;                                       // each elem counted by both halves
        sumsq = fmaf(y, y, sumsq);
    }

    // in-wave butterfly; every element was added by both halves -> scale 0.5
#pragma unroll
    for (int off = 1; off < 64; off <<= 1) {
        sum   += __shfl_xor(sum, off, 64);
        sumsq += __shfl_xor(sumsq, off, 64);
    }

    const float inv  = 0.5f / (float)CDIM;
    const float mu   = sum * inv;
    const float var  = fmaf(sumsq, inv, -mu * mu);
    const float rstd = rsqrtf(var + LN_EPS);

    // coalesced epilogue: contiguous float2 reads from LDS, float2 stores
    float2* __restrict__ yr2 = reinterpret_cast<float2*>(out + (size_t)row * CDIM);
    const float2* __restrict__ g2 = reinterpret_cast<const float2*>(gamma);
    const float2* __restrict__ b2 = reinterpret_cast<const float2*>(beta);
#pragma unroll
    for (int qq = 0; qq < 7; ++qq) {
        const int i = lane + 64 * qq;
        if (i < CDIM / 2) {
            const float2 yv = *reinterpret_cast<const float2*>(&sxy[wv][2 * i]);
            const float2 gv = g2[i];
            const float2 bv = b2[i];
            float2 o;
            o.x = fmaf((yv.x - mu) * rstd, gv.x, bv.x);
            o.y = fmaf((yv.y - mu) * rstd, gv.y, bv.y);
            yr2[i] = o;
        }
    }
}

extern "C" void kernel_launch(void* const* d_in, const int* in_sizes, int n_in,
                              void* d_out, int out_size, void* d_ws, size_t ws_size,
                              hipStream_t stream) {
    const float* x     = (const float*)d_in[0];
    const float* Wup   = (const float*)d_in[1];
    const float* bup   = (const float*)d_in[2];
    const float* Wdown = (const float*)d_in[3];
    const float* bdown = (const float*)d_in[4];
    const float* gamma = (const float*)d_in[5];
    const float* beta  = (const float*)d_in[6];
    float* out = (float*)d_out;

    const int nrows = out_size / CDIM;                 // 11520 (divisible by 4)
    const int nblk  = nrows / ROWS_PER_BLOCK;          // 2880
    cvmc_kernel<<<nblk, THREADS, 0, stream>>>(x, Wup, bup, Wdown, bdown,
                                              gamma, beta, out);
}

// Round 16
// 38.343 us; speedup vs baseline: 1.1547x; 1.1547x over previous
//
#include <hip/hip_runtime.h>
#include <math.h>

#define CDIM   862
#define NRANK  8
#define KW     7
#define ROWS_PER_BLOCK 4
#define THREADS (ROWS_PER_BLOCK * 64)
#define LN_EPS 1e-5f
#define NPAIRT 13            // 13 double-tiles cover elements 0..831
#define XH_LEN 880           // shorts: [0..3] zero pad, [4+i]=bf16(x[i]), zeros to 879
#define XY_LEN 866           // f32: x (later overwritten by pre-norm y), + pad

typedef __attribute__((ext_vector_type(8)))  short bf16x8;
typedef __attribute__((ext_vector_type(16))) float f32x16;

static __device__ __forceinline__ unsigned rne_bf16(float f) {
    const unsigned u = __float_as_uint(f);
    return (u + 0x7FFFu + ((u >> 16) & 1u)) >> 16;   // round-to-nearest-even
}

// One wave = one row. DOUBLE-TILE MFMA: A(32x16) holds Wup twice --
// rows 0-7 at k=0..6 and rows 8-15 at k=8..14. B column c: k=0..7 slots
// (lanes 0-31) = window of element 64s+l31, k=8..15 slots (lanes 32-63) =
// window of element 64s+32+l31 -> every lane extracts the window of element
// 64s+lane (uniform, no half-duplication). One mfma_32x32x16_bf16 then yields
// 64 elements x 8 ranks: lane gets d[0..3] = ranks 4*hh..4*hh+3 of element
// 64s+l31 and d[4..7] = same ranks of +32 (D row=(reg&3)+8*(reg>>2)+4*hh,
// m74/m101-verified). Down-proj closes with 2 shfl_xor(32); each lane then
// owns exactly one element's y (no double counting). Bias via MFMA C-operand.
__global__ __launch_bounds__(THREADS) void cvmc_kernel(
    const float* __restrict__ x,
    const float* __restrict__ Wup,
    const float* __restrict__ bup,
    const float* __restrict__ Wdown,
    const float* __restrict__ bdown,
    const float* __restrict__ gamma,
    const float* __restrict__ beta,
    float* __restrict__ out)
{
    const int lane = threadIdx.x & 63;
    const int wv   = threadIdx.x >> 6;
    const int row  = blockIdx.x * ROWS_PER_BLOCK + wv;

    __shared__ short sxh[ROWS_PER_BLOCK][XH_LEN];
    __shared__ float sxy[ROWS_PER_BLOCK][XY_LEN];

    const int hh    = lane >> 5;
    const int l31   = lane & 31;
    const int rbase = 4 * hh;          // this half-wave's rank group
    float bu4[4], wd4[4];
#pragma unroll
    for (int q = 0; q < 4; ++q) {
        bu4[q] = bup[rbase + q];
        wd4[q] = Wdown[rbase + q];
    }
    const float bdv = bdown[0];

    // ---- A fragment: rows 0-7 @ k=0..6 (hh=0 slots), rows 8-15 @ k=8..14 (hh=1) ----
    bf16x8 afrag;
    {
        const bool use = (hh == 0) ? (l31 < NRANK) : (l31 >= 8 && l31 < 8 + NRANK);
        const int  rr  = (hh == 0) ? l31 : (l31 - 8);
#pragma unroll
        for (int j = 0; j < 8; ++j) {
            float wvv = (use && j < KW) ? Wup[rr * KW + j] : 0.0f;
            afrag[j] = (short)(rne_bf16(wvv) & 0xFFFFu);
        }
    }

    // ---- C operand: bias per D row (rank = (q&3)+rbase for q<8), rest 0 ----
    f32x16 cin;
#pragma unroll
    for (int i = 0; i < 16; ++i) cin[i] = 0.0f;
#pragma unroll
    for (int q = 0; q < 8; ++q) cin[q] = bu4[q & 3];

    // ---- stage row: sxy = f32 x, sxh = bf16(RNE) with 4-short left pad ----
    {
        const float2* __restrict__ xr2 =
            reinterpret_cast<const float2*>(x + (size_t)row * CDIM);
        unsigned* xhW = reinterpret_cast<unsigned*>(&sxh[wv][0]);
#pragma unroll
        for (int qq = 0; qq < 7; ++qq) {
            const int i = lane + 64 * qq;               // float2 pair index
            if (i < CDIM / 2) {
                float2 v = xr2[i];
                *reinterpret_cast<float2*>(&sxy[wv][2 * i]) = v;
                xhW[2 + i] = rne_bf16(v.x) | (rne_bf16(v.y) << 16);
            }
        }
        if (lane < 2)       xhW[lane] = 0u;             // shorts 0..3 (left halo)
        else if (lane < 9)  xhW[431 + lane] = 0u;       // shorts 866..879 zero
        else if (lane < 13) sxy[wv][862 + (lane - 9)] = 0.0f;
    }
    // wave-private LDS slice; same-wave DS ops are in issue order -> no barrier

    const float C1 = -0.0713548162f;   // gelu(t) ~ t*sigmoid(1.5957691 t + 0.07135482 t^3)
    const float C0 = -1.5957691216f;

    const unsigned* xhD = reinterpret_cast<const unsigned*>(&sxh[wv][0]);

    // per-4-rank GELU + down-proj partial (math identical to r6-r15)
    auto dp4 = [&](float t0, float t1, float t2, float t3) -> float {
        const float z0 = t0 * fmaf(t0 * t0, C1, C0);
        const float z1 = t1 * fmaf(t1 * t1, C1, C0);
        const float z2 = t2 * fmaf(t2 * t2, C1, C0);
        const float z3 = t3 * fmaf(t3 * t3, C1, C0);
        const float u0 = 1.0f + __expf(z0);
        const float u1 = 1.0f + __expf(z1);
        const float u2 = 1.0f + __expf(z2);
        const float u3 = 1.0f + __expf(z3);
        const float r01 = __builtin_amdgcn_rcpf(u0 * u1);
        const float r23 = __builtin_amdgcn_rcpf(u2 * u3);
        float n0 = (wd4[0] * t0) * u1; n0 = fmaf(wd4[1] * t1, u0, n0);
        float n1 = (wd4[2] * t2) * u3; n1 = fmaf(wd4[3] * t3, u2, n1);
        float p  = n0 * r01;
        return fmaf(n1, r23, p);
    };

    float sum = 0.0f, sumsq = 0.0f;

    for (int s = 0; s < NPAIRT; ++s) {
        const int cw = 64 * s + lane;      // this lane's window element (= its y element)
        const int ws = cw + 1;             // short index of x[cw-3] in sxh

        const unsigned* pw = xhD + (ws >> 1);
        const unsigned sh = (unsigned)(ws & 1) * 16u;
        const unsigned q0 = pw[0], q1 = pw[1], q2 = pw[2], q3 = pw[3], q4 = pw[4];
        union { unsigned u[4]; bf16x8 v; } bfr;
        bfr.u[0] = __builtin_amdgcn_alignbit(q1, q0, sh);
        bfr.u[1] = __builtin_amdgcn_alignbit(q2, q1, sh);
        bfr.u[2] = __builtin_amdgcn_alignbit(q3, q2, sh);
        bfr.u[3] = __builtin_amdgcn_alignbit(q4, q3, sh);

        f32x16 d = __builtin_amdgcn_mfma_f32_32x32x16_bf16(afrag, bfr.v, cin, 0, 0, 0);

        // d[0..3]: ranks rbase.. of eA=64s+l31 ; d[4..7]: same ranks of eB=eA+32
        const float pA = dp4(d[0], d[1], d[2], d[3]);
        const float pB = dp4(d[4], d[5], d[6], d[7]);
        const float hA = pA + __shfl_xor(pA, 32, 64);
        const float hB = pB + __shfl_xor(pB, 32, 64);
        const float h  = (hh == 0) ? hA : hB;          // this lane's element = cw

        const float xv = sxy[wv][cw];
        const float y  = xv + bdv + h;
        sxy[wv][cw] = y;
        sum += y;
        sumsq = fmaf(y, y, sumsq);
    }

    // ---- tail tile: elements 832..861 (single-tile path, halves duplicate) ----
    {
        const int c  = 832 + l31;
        const int ws = c + 1;
        const unsigned* pw = xhD + (ws >> 1);
        const unsigned sh = (unsigned)(ws & 1) * 16u;
        const unsigned q0 = pw[0], q1 = pw[1], q2 = pw[2], q3 = pw[3], q4 = pw[4];
        union { unsigned u[4]; bf16x8 v; } bfr;
        bfr.u[0] = __builtin_amdgcn_alignbit(q1, q0, sh);
        bfr.u[1] = __builtin_amdgcn_alignbit(q2, q1, sh);
        bfr.u[2] = __builtin_amdgcn_alignbit(q3, q2, sh);
        bfr.u[3] = __builtin_amdgcn_alignbit(q4, q3, sh);

        f32x16 d = __builtin_amdgcn_mfma_f32_32x32x16_bf16(afrag, bfr.v, cin, 0, 0, 0);

        const float p = dp4(d[0], d[1], d[2], d[3]);
        const float psum = p + __shfl_xor(p, 32, 64);
        const float y = sxy[wv][c] + bdv + psum;
        if (hh == 0 && c < CDIM) {                     // single-counted
            sxy[wv][c] = y;
            sum += y;
            sumsq = fmaf(y, y, sumsq);
        }
    }

    // in-wave butterfly: every lane ends with the row totals
#pragma unroll
    for (int off = 1; off < 64; off <<= 1) {
        sum   += __shfl_xor(sum, off, 64);
        sumsq += __shfl_xor(sumsq, off, 64);
    }

    const float inv  = 1.0f / (float)CDIM;
    const float mu   = sum * inv;
    const float var  = fmaf(sumsq, inv, -mu * mu);
    const float rstd = rsqrtf(var + LN_EPS);

    // coalesced epilogue: contiguous float2 reads from LDS, float2 stores
    float2* __restrict__ yr2 = reinterpret_cast<float2*>(out + (size_t)row * CDIM);
    const float2* __restrict__ g2 = reinterpret_cast<const float2*>(gamma);
    const float2* __restrict__ b2 = reinterpret_cast<const float2*>(beta);
#pragma unroll
    for (int qq = 0; qq < 7; ++qq) {
        const int i = lane + 64 * qq;
        if (i < CDIM / 2) {
            const float2 yv = *reinterpret_cast<const float2*>(&sxy[wv][2 * i]);
            const float2 gv = g2[i];
            const float2 bv = b2[i];
            float2 o;
            o.x = fmaf((yv.x - mu) * rstd, gv.x, bv.x);
            o.y = fmaf((yv.y - mu) * rstd, gv.y, bv.y);
            yr2[i] = o;
        }
    }
}

extern "C" void kernel_launch(void* const* d_in, const int* in_sizes, int n_in,
                              void* d_out, int out_size, void* d_ws, size_t ws_size,
                              hipStream_t stream) {
    const float* x     = (const float*)d_in[0];
    const float* Wup   = (const float*)d_in[1];
    const float* bup   = (const float*)d_in[2];
    const float* Wdown = (const float*)d_in[3];
    const float* bdown = (const float*)d_in[4];
    const float* gamma = (const float*)d_in[5];
    const float* beta  = (const float*)d_in[6];
    float* out = (float*)d_out;

    const int nrows = out_size / CDIM;                 // 11520 (divisible by 4)
    const int nblk  = nrows / ROWS_PER_BLOCK;          // 2880
    cvmc_kernel<<<nblk, THREADS, 0, stream>>>(x, Wup, bup, Wdown, bdown,
                                              gamma, beta, out);
}